// Round 1
// baseline (394.464 us; speedup 1.0000x reference)
//
#include <hip/hip_runtime.h>
#include <hip/hip_bf16.h>
#include <stdint.h>

typedef float f32x4 __attribute__((ext_vector_type(4)));
typedef __bf16 bf16x8 __attribute__((ext_vector_type(8)));

#define GLDS16(gp, lp) __builtin_amdgcn_global_load_lds( \
    (const __attribute__((address_space(1))) void*)(gp), \
    (__attribute__((address_space(3))) void*)(lp), 16, 0, 0)

static __device__ __forceinline__ unsigned short f2bf(float f) {
    unsigned int u = __float_as_uint(f);
    u = (u + 0x7fffu + ((u >> 16) & 1u)) >> 16;
    return (unsigned short)u;
}
static __device__ __forceinline__ float bf2f(unsigned short v) {
    return __uint_as_float(((unsigned int)v) << 16);
}

// ---------------- workspace layout (bytes) ----------------
// styles : 16x512 f32                      @ 0        (32 KB)
// wsq    : 512x512 f32                     @ 32768    (1 MB)
// dcoefs : 16x512 f32                      @ 1081344  (32 KB)
// xs_pad : 16x34x34x512 bf16 (NHWC, +1 halo) @ 1114112 (18.06 MB)
// wp     : 9x512x512 bf16 ([tap][co][ci])  @ 20054016 (4.5 MB)
// y1     : 16x4x1089x512 bf16 (parity planes, [r*33+s][co]) @ 24772608 (68.06 MB)
#define O_STYLES 0
#define O_WSQ    32768
#define O_DCOEF  1081344
#define O_XS     1114112
#define O_WP     20054016
#define O_Y1     24772608
#define WS_NEED  96141312

// K0: styles[b][ci] = w[b]·A[ci]/sqrt(512) + bias[ci]
__global__ __launch_bounds__(256) void k_styles(const float* __restrict__ w,
                                                const float* __restrict__ aw,
                                                const float* __restrict__ ab,
                                                float* __restrict__ styles) {
    int g = blockIdx.x * 256 + threadIdx.x;   // 8192
    int b = g >> 9, ci = g & 511;
    const float4* wr = (const float4*)(w + b * 512);
    const float4* ar = (const float4*)(aw + ci * 512);
    float acc = 0.f;
    for (int k = 0; k < 128; ++k) {
        float4 wv = wr[k], av = ar[k];
        acc += wv.x * av.x + wv.y * av.y + wv.z * av.z + wv.w * av.w;
    }
    styles[g] = acc * 0.04419417382415922f + ab[ci];
}

// K1: per (co,ci): wsq = sum of 9 squared taps; wp[tap][co][ci] = bf16(weight tap)
__global__ __launch_bounds__(256) void k_wprep(const float* __restrict__ weight,
                                               float* __restrict__ wsq,
                                               unsigned short* __restrict__ wp) {
    int g = blockIdx.x * 256 + threadIdx.x;   // 262144 = co*512+ci
    const float* wb = weight + (long)g * 9;
    float v[9]; float s = 0.f;
#pragma unroll
    for (int t = 0; t < 9; ++t) { v[t] = wb[t]; s += v[t] * v[t]; }
    wsq[g] = s;
    // global tap order: par0 (ee): (2,2)(2,0)(0,2)(0,0); par1 (eo): (2,1)(0,1);
    // par2 (oe): (1,2)(1,0); par3 (oo): (1,1)
    const int wri[9] = {2, 2, 0, 0, 2, 0, 1, 1, 1};
    const int wci[9] = {2, 0, 2, 0, 1, 1, 2, 0, 1};
#pragma unroll
    for (int t = 0; t < 9; ++t)
        wp[t * 262144 + g] = f2bf(v[wri[t] * 3 + wci[t]]);
}

// K2: dcoefs[b][co] = rsqrt(sum_ci styles^2 * wsq + 1e-8)
__global__ __launch_bounds__(256) void k_dcoef(const float* __restrict__ styles,
                                               const float* __restrict__ wsq,
                                               float* __restrict__ dcoefs) {
    int g = blockIdx.x * 256 + threadIdx.x;   // 8192
    int b = g >> 9, co = g & 511;
    const float4* sr = (const float4*)(styles + b * 512);
    const float4* qr = (const float4*)(wsq + co * 512);
    float acc = 1e-8f;
    for (int k = 0; k < 128; ++k) {
        float4 sv = sr[k], qv = qr[k];
        acc += sv.x * sv.x * qv.x + sv.y * sv.y * qv.y + sv.z * sv.z * qv.z + sv.w * sv.w * qv.w;
    }
    dcoefs[g] = rsqrtf(acc);
}

// K3: xs_pad[b][i+1][j+1][ci] = bf16(x[b][ci][i][j] * styles[b][ci])  (NCHW->NHWC via LDS)
__global__ __launch_bounds__(256) void k_xprep(const float* __restrict__ x,
                                               const float* __restrict__ styles,
                                               unsigned short* __restrict__ xs) {
    __shared__ float T[128][33];
    int bid = blockIdx.x;                 // 16*32*4
    int cc = bid & 3, i = (bid >> 2) & 31, b = bid >> 7;
    int t = threadIdx.x;
    int ci0 = cc * 128;
    int j_r = t & 31, cl_r = t >> 5;
    const float* xp = x + (((long)(b * 512 + ci0)) * 32 + i) * 32;
#pragma unroll
    for (int it = 0; it < 16; ++it) {
        int cl = cl_r + it * 8;
        T[cl][j_r] = xp[cl * 1024 + j_r];
    }
    __syncthreads();
    int ci_w = t & 127, jg = t >> 7;
    float sv = styles[b * 512 + ci0 + ci_w];
    unsigned short* op = xs + (((long)(b * 34 + (i + 1))) * 34 + 1) * 512 + ci0 + ci_w;
#pragma unroll
    for (int jj = 0; jj < 16; ++jj) {
        int j = jg * 16 + jj;
        op[(long)j * 512] = f2bf(T[ci_w][j] * sv);
    }
}

// K5: stage-1 implicit GEMM. Per (b, parity): C[pixel][co] += A[pixel][tap,ci] * W[tap,ci][co]
// BM=128 pixels, BN=128 co, BK=32 ci. 4 waves, each 64x64 (4x4 frags of 16x16x32 bf16).
__global__ __launch_bounds__(256) void k_conv(const unsigned short* __restrict__ xs,
                                              const unsigned short* __restrict__ wp,
                                              unsigned short* __restrict__ y1) {
    __shared__ __align__(16) unsigned char lds[16384];   // A: [0,8K) B: [8K,16K)
    int bid = blockIdx.x;                 // ((b*4+par)*9+mt)*4+nt
    int nt = bid & 3;
    int tmp = bid >> 2;
    int mt = tmp % 9;
    int tmp2 = tmp / 9;
    int par = tmp2 & 3, b = tmp2 >> 2;
    int tid = threadIdx.x;
    int wave = tid >> 6, lane = tid & 63;

    // per-thread A/B global bases (chunk tid -> row tid>>2; chunk tid+256 -> row+64)
    const int coff = (tid & 3) * 16;
    long abase0, abase1, bbase0, bbase1;
    {
        int row0 = tid >> 2;
        int gm0 = mt * 128 + row0;
        int r0 = gm0 / 33, s0 = gm0 % 33; if (r0 > 32) r0 = 32;
        int gm1 = gm0 + 64;
        int r1 = gm1 / 33, s1 = gm1 % 33; if (r1 > 32) r1 = 32;
        abase0 = (long)(((b * 34 + r0) * 34 + s0)) * 1024 + coff;
        abase1 = (long)(((b * 34 + r1) * 34 + s1)) * 1024 + coff;
        int co0 = nt * 128 + row0;
        bbase0 = (long)co0 * 1024 + coff;
        bbase1 = (long)(co0 + 64) * 1024 + coff;
    }
    const unsigned char* xsb = (const unsigned char*)xs;
    const unsigned char* wpb = (const unsigned char*)wp;

    int a_par = par >> 1, c_par = par & 1;
    int ntaps = a_par ? (c_par ? 1 : 2) : (c_par ? 2 : 4);
    int tapofs = (par == 0) ? 0 : ((par == 1) ? 4 : ((par == 2) ? 6 : 8));
    int KT = ntaps << 4;

    f32x4 acc[4][4];
#pragma unroll
    for (int mi = 0; mi < 4; ++mi)
#pragma unroll
        for (int ni = 0; ni < 4; ++ni)
            acc[mi][ni] = (f32x4){0.f, 0.f, 0.f, 0.f};

    int wr = wave >> 1, wc = wave & 1;
    int lrow = lane & 15;
    int lk = (lane >> 4) * 16;

    for (int kt = 0; kt < KT; ++kt) {
        int tl = kt >> 4, cib = kt & 15;
        int dio = a_par ? 1 : (c_par ? tl : (tl >> 1));
        int djo = c_par ? 1 : (a_par ? tl : (tl & 1));
        long dd = (long)dio * 34816 + (long)djo * 1024 + cib * 64;
        long wd = (long)(tapofs + tl) * 524288 + cib * 64;
        GLDS16(xsb + abase0 + dd, lds + wave * 1024);
        GLDS16(xsb + abase1 + dd, lds + 4096 + wave * 1024);
        GLDS16(wpb + bbase0 + wd, lds + 8192 + wave * 1024);
        GLDS16(wpb + bbase1 + wd, lds + 12288 + wave * 1024);
        __syncthreads();
        bf16x8 af[4], bfr[4];
#pragma unroll
        for (int mi = 0; mi < 4; ++mi)
            af[mi] = *(const bf16x8*)(lds + (wr * 64 + mi * 16 + lrow) * 64 + lk);
#pragma unroll
        for (int ni = 0; ni < 4; ++ni)
            bfr[ni] = *(const bf16x8*)(lds + 8192 + (wc * 64 + ni * 16 + lrow) * 64 + lk);
#pragma unroll
        for (int mi = 0; mi < 4; ++mi)
#pragma unroll
            for (int ni = 0; ni < 4; ++ni)
                acc[mi][ni] = __builtin_amdgcn_mfma_f32_16x16x32_bf16(af[mi], bfr[ni], acc[mi][ni], 0, 0, 0);
        __syncthreads();
    }

    // epilogue: D row=(lane>>4)*4+j (pixel), col=lane&15 (co)
    long plane = (long)(b * 4 + par) * 1089;
#pragma unroll
    for (int mi = 0; mi < 4; ++mi) {
#pragma unroll
        for (int ni = 0; ni < 4; ++ni) {
            int co = nt * 128 + wc * 64 + ni * 16 + (lane & 15);
#pragma unroll
            for (int j = 0; j < 4; ++j) {
                int gm = mt * 128 + wr * 64 + mi * 16 + (lane >> 4) * 4 + j;
                if (gm < 1089)
                    y1[(plane + gm) * 512 + co] = f2bf(acc[mi][ni][j]);
            }
        }
    }
}

// K6: blur(4x4 bilinear) + demod + noise + bias + leaky. Reads parity planes, writes NCHW f32.
__global__ __launch_bounds__(256) void k_blur(const unsigned short* __restrict__ y1,
                                              const float* __restrict__ dcoefs,
                                              const float* __restrict__ bias,
                                              const float* __restrict__ noise,
                                              const float* __restrict__ nstr,
                                              float* __restrict__ out) {
    __shared__ float T[64][65];
    int bid = blockIdx.x;                 // ((b*8+coch)*8+mch)
    int mch = bid & 7, coch = (bid >> 3) & 7, b = bid >> 6;
    int t = threadIdx.x;
    int co_l = t & 63, nq = t >> 6;
    int co = coch * 64 + co_l;
    float dc = dcoefs[b * 512 + co];
    float bi = bias[co];
    float ns = nstr[0];
    const unsigned short* yb = y1 + (long)(b * 4) * 1089 * 512 + co;
    const float* np_ = noise + b * 4096;
    const float hc[4] = {1.f, 3.f, 3.f, 1.f};

    for (int ml = 0; ml < 8; ++ml) {
        int m = mch * 8 + ml;
        float pre[16];
#pragma unroll
        for (int k = 0; k < 16; ++k) pre[k] = 0.f;
        int q0 = nq * 16 - 1;
#pragma unroll
        for (int u = 0; u < 4; ++u) {
            int p = m + u - 1;
            if (p < 0 || p >= 65) continue;
            int ap = p & 1, r = p >> 1;
            long rowbase = ((long)(ap * 2) * 1089 + (long)r * 33) * 512;
            float hu = hc[u];
#pragma unroll
            for (int qi = 0; qi < 19; ++qi) {
                int q = q0 + qi;
                float yv = 0.f;
                if (q >= 0 && q < 65) {
                    int cq = q & 1, s = q >> 1;
                    yv = bf2f(yb[rowbase + ((long)cq * 1089 + s) * 512]);
                }
#pragma unroll
                for (int v = 0; v < 4; ++v) {
                    int k = qi - v;
                    if (k >= 0 && k < 16) pre[k] += hu * hc[v] * yv;
                }
            }
        }
#pragma unroll
        for (int k = 0; k < 16; ++k) {
            int n = nq * 16 + k;
            float val = np_[m * 64 + n] * ns + pre[k] * (1.f / 16.f) * dc;
            val = (val + bi) * 1.41421356237309515f;
            T[co_l][n] = (val >= 0.f) ? val : 0.2f * val;
        }
        __syncthreads();
        int n_w = t & 63, cg = t >> 6;
#pragma unroll
        for (int k2 = 0; k2 < 16; ++k2) {
            int co_w = cg * 16 + k2;
            out[(((long)(b * 512 + coch * 64 + co_w)) * 64 + m) * 64 + n_w] = T[co_w][n_w];
        }
        __syncthreads();
    }
}

extern "C" void kernel_launch(void* const* d_in, const int* in_sizes, int n_in,
                              void* d_out, int out_size, void* d_ws, size_t ws_size,
                              hipStream_t stream) {
    (void)in_sizes; (void)n_in; (void)out_size;
    if (ws_size < (size_t)WS_NEED) return;   // workspace too small: fail cleanly
    const float* x      = (const float*)d_in[0];
    const float* w      = (const float*)d_in[1];
    const float* noise  = (const float*)d_in[2];
    const float* aw     = (const float*)d_in[3];
    const float* ab     = (const float*)d_in[4];
    const float* weight = (const float*)d_in[5];
    const float* bias   = (const float*)d_in[6];
    const float* nstr   = (const float*)d_in[7];
    float* out = (float*)d_out;
    char* ws = (char*)d_ws;
    float* styles          = (float*)(ws + O_STYLES);
    float* wsq             = (float*)(ws + O_WSQ);
    float* dcoefs          = (float*)(ws + O_DCOEF);
    unsigned short* xs     = (unsigned short*)(ws + O_XS);
    unsigned short* wp     = (unsigned short*)(ws + O_WP);
    unsigned short* y1     = (unsigned short*)(ws + O_Y1);

    hipMemsetAsync(xs, 0, 18939904, stream);
    k_styles<<<32,   256, 0, stream>>>(w, aw, ab, styles);
    k_wprep <<<1024, 256, 0, stream>>>(weight, wsq, wp);
    k_dcoef <<<32,   256, 0, stream>>>(styles, wsq, dcoefs);
    k_xprep <<<2048, 256, 0, stream>>>(x, styles, xs);
    k_conv  <<<2304, 256, 0, stream>>>(xs, wp, y1);
    k_blur  <<<1024, 256, 0, stream>>>(y1, dcoefs, bias, noise, nstr, out);
}

// Round 2
// 222.236 us; speedup vs baseline: 1.7750x; 1.7750x over previous
//
#include <hip/hip_runtime.h>
#include <hip/hip_bf16.h>
#include <stdint.h>

typedef float f32x4 __attribute__((ext_vector_type(4)));
typedef __bf16 bf16x8 __attribute__((ext_vector_type(8)));

#define GLDS16(gp, lp) __builtin_amdgcn_global_load_lds( \
    (const __attribute__((address_space(1))) void*)(gp), \
    (__attribute__((address_space(3))) void*)(lp), 16, 0, 0)

static __device__ __forceinline__ unsigned short f2bf(float f) {
    unsigned int u = __float_as_uint(f);
    u = (u + 0x7fffu + ((u >> 16) & 1u)) >> 16;
    return (unsigned short)u;
}
static __device__ __forceinline__ float bf2f(unsigned short v) {
    return __uint_as_float(((unsigned int)v) << 16);
}

// ---------------- workspace layout (bytes) ----------------
// styles : 16x512 f32                          @ 0
// dcoefs : 16x512 f32                          @ 32768
// xs_pad : 16x34x34x512 bf16 (NHWC, +1 halo)   @ 65536      (18.06 MB)
// wp     : 9x512x512 bf16 ([tap][co][ci])      @ 19005440   (4.5 MB)
// y1T    : 16x4x512x1104 bf16 ([b][pl][co][pix]) @ 23724032 (72.35 MB)
// wsq    : 512x512 f32 — OVERLAPPED into y1T region (consumed by k_dcoef
//          strictly before k_conv writes y1T; stream-ordered, deterministic)
#define O_STYLES 0
#define O_DCOEF  32768
#define O_XS     65536
#define O_WP     19005440
#define O_Y1     23724032
#define O_WSQ    23724032
#define WS_NEED  96075776
#define SP 1104   // y1T pixel stride per co (69*16 elems -> 2208B, 32B-aligned)

// K0: styles[b][ci] = w[b]·A[ci]/sqrt(512) + bias[ci]
__global__ __launch_bounds__(256) void k_styles(const float* __restrict__ w,
                                                const float* __restrict__ aw,
                                                const float* __restrict__ ab,
                                                float* __restrict__ styles) {
    int g = blockIdx.x * 256 + threadIdx.x;   // 8192
    int b = g >> 9, ci = g & 511;
    const float4* wr = (const float4*)(w + b * 512);
    const float4* ar = (const float4*)(aw + ci * 512);
    float acc = 0.f;
    for (int k = 0; k < 128; ++k) {
        float4 wv = wr[k], av = ar[k];
        acc += wv.x * av.x + wv.y * av.y + wv.z * av.z + wv.w * av.w;
    }
    styles[g] = acc * 0.04419417382415922f + ab[ci];
}

// K1: per (co,ci): wsq = sum of 9 squared taps; wp[tap][co][ci] = bf16(weight tap)
__global__ __launch_bounds__(256) void k_wprep(const float* __restrict__ weight,
                                               float* __restrict__ wsq,
                                               unsigned short* __restrict__ wp) {
    int g = blockIdx.x * 256 + threadIdx.x;   // 262144 = co*512+ci
    const float* wb = weight + (long)g * 9;
    float v[9]; float s = 0.f;
#pragma unroll
    for (int t = 0; t < 9; ++t) { v[t] = wb[t]; s += v[t] * v[t]; }
    wsq[g] = s;
    // global tap order: par0 (ee): (2,2)(2,0)(0,2)(0,0); par1 (eo): (2,1)(0,1);
    // par2 (oe): (1,2)(1,0); par3 (oo): (1,1)
    const int wri[9] = {2, 2, 0, 0, 2, 0, 1, 1, 1};
    const int wci[9] = {2, 0, 2, 0, 1, 1, 2, 0, 1};
#pragma unroll
    for (int t = 0; t < 9; ++t)
        wp[t * 262144 + g] = f2bf(v[wri[t] * 3 + wci[t]]);
}

// K2: dcoefs[b][co] = rsqrt(sum_ci styles^2 * wsq + 1e-8)
__global__ __launch_bounds__(256) void k_dcoef(const float* __restrict__ styles,
                                               const float* __restrict__ wsq,
                                               float* __restrict__ dcoefs) {
    int g = blockIdx.x * 256 + threadIdx.x;   // 8192
    int b = g >> 9, co = g & 511;
    const float4* sr = (const float4*)(styles + b * 512);
    const float4* qr = (const float4*)(wsq + co * 512);
    float acc = 1e-8f;
    for (int k = 0; k < 128; ++k) {
        float4 sv = sr[k], qv = qr[k];
        acc += sv.x * sv.x * qv.x + sv.y * sv.y * qv.y + sv.z * sv.z * qv.z + sv.w * sv.w * qv.w;
    }
    dcoefs[g] = rsqrtf(acc);
}

// K3: xs_pad[b][i+1][j+1][ci] = bf16(x[b][ci][i][j] * styles[b][ci])  (NCHW->NHWC via LDS)
__global__ __launch_bounds__(256) void k_xprep(const float* __restrict__ x,
                                               const float* __restrict__ styles,
                                               unsigned short* __restrict__ xs) {
    __shared__ float T[128][33];
    int bid = blockIdx.x;                 // 16*32*4
    int cc = bid & 3, i = (bid >> 2) & 31, b = bid >> 7;
    int t = threadIdx.x;
    int ci0 = cc * 128;
    int j_r = t & 31, cl_r = t >> 5;
    const float* xp = x + (((long)(b * 512 + ci0)) * 32 + i) * 32;
#pragma unroll
    for (int it = 0; it < 16; ++it) {
        int cl = cl_r + it * 8;
        T[cl][j_r] = xp[cl * 1024 + j_r];
    }
    __syncthreads();
    int ci_w = t & 127, jg = t >> 7;
    float sv = styles[b * 512 + ci0 + ci_w];
    unsigned short* op = xs + (((long)(b * 34 + (i + 1))) * 34 + 1) * 512 + ci0 + ci_w;
#pragma unroll
    for (int jj = 0; jj < 16; ++jj) {
        int j = jg * 16 + jj;
        op[(long)j * 512] = f2bf(T[ci_w][j] * sv);
    }
}

// K5: stage-1 implicit GEMM. Per (b, parity): C[pixel][co] += A[pixel][tap,ci] * W[tap,ci][co]
// BM=128 pixels, BN=128 co, BK=32 ci. 4 waves, each 64x64 (4x4 frags of 16x16x32 bf16).
// Output: y1T[b][pl][co][pix] (co-major, pix-stride SP).
__global__ __launch_bounds__(256) void k_conv(const unsigned short* __restrict__ xs,
                                              const unsigned short* __restrict__ wp,
                                              unsigned short* __restrict__ y1) {
    __shared__ __align__(16) unsigned char lds[16384];   // A: [0,8K) B: [8K,16K)
    // XCD-aware bijective swizzle (2304 % 8 == 0)
    int bid = (blockIdx.x & 7) * 288 + (blockIdx.x >> 3);
    int nt = bid & 3;
    int tmp = bid >> 2;
    int mt = tmp % 9;
    int tmp2 = tmp / 9;
    int par = tmp2 & 3, b = tmp2 >> 2;
    int tid = threadIdx.x;
    int wave = tid >> 6, lane = tid & 63;

    // per-thread A/B global bases (chunk tid -> row tid>>2; chunk tid+256 -> row+64)
    const int coff = (tid & 3) * 16;
    long abase0, abase1, bbase0, bbase1;
    {
        int row0 = tid >> 2;
        int gm0 = mt * 128 + row0;
        int r0 = gm0 / 33, s0 = gm0 % 33; if (r0 > 32) r0 = 32;
        int gm1 = gm0 + 64;
        int r1 = gm1 / 33, s1 = gm1 % 33; if (r1 > 32) r1 = 32;
        abase0 = (long)(((b * 34 + r0) * 34 + s0)) * 1024 + coff;
        abase1 = (long)(((b * 34 + r1) * 34 + s1)) * 1024 + coff;
        int co0 = nt * 128 + row0;
        bbase0 = (long)co0 * 1024 + coff;
        bbase1 = (long)(co0 + 64) * 1024 + coff;
    }
    const unsigned char* xsb = (const unsigned char*)xs;
    const unsigned char* wpb = (const unsigned char*)wp;

    int a_par = par >> 1, c_par = par & 1;
    int ntaps = a_par ? (c_par ? 1 : 2) : (c_par ? 2 : 4);
    int tapofs = (par == 0) ? 0 : ((par == 1) ? 4 : ((par == 2) ? 6 : 8));
    int KT = ntaps << 4;

    f32x4 acc[4][4];
#pragma unroll
    for (int mi = 0; mi < 4; ++mi)
#pragma unroll
        for (int ni = 0; ni < 4; ++ni)
            acc[mi][ni] = (f32x4){0.f, 0.f, 0.f, 0.f};

    int wr = wave >> 1, wc = wave & 1;
    int lrow = lane & 15;
    int lk = (lane >> 4) * 16;

    for (int kt = 0; kt < KT; ++kt) {
        int tl = kt >> 4, cib = kt & 15;
        int dio = a_par ? 1 : (c_par ? tl : (tl >> 1));
        int djo = c_par ? 1 : (a_par ? tl : (tl & 1));
        long dd = (long)dio * 34816 + (long)djo * 1024 + cib * 64;
        long wd = (long)(tapofs + tl) * 524288 + cib * 64;
        GLDS16(xsb + abase0 + dd, lds + wave * 1024);
        GLDS16(xsb + abase1 + dd, lds + 4096 + wave * 1024);
        GLDS16(wpb + bbase0 + wd, lds + 8192 + wave * 1024);
        GLDS16(wpb + bbase1 + wd, lds + 12288 + wave * 1024);
        __syncthreads();
        bf16x8 af[4], bfr[4];
#pragma unroll
        for (int mi = 0; mi < 4; ++mi)
            af[mi] = *(const bf16x8*)(lds + (wr * 64 + mi * 16 + lrow) * 64 + lk);
#pragma unroll
        for (int ni = 0; ni < 4; ++ni)
            bfr[ni] = *(const bf16x8*)(lds + 8192 + (wc * 64 + ni * 16 + lrow) * 64 + lk);
#pragma unroll
        for (int mi = 0; mi < 4; ++mi)
#pragma unroll
            for (int ni = 0; ni < 4; ++ni)
                acc[mi][ni] = __builtin_amdgcn_mfma_f32_16x16x32_bf16(af[mi], bfr[ni], acc[mi][ni], 0, 0, 0);
        __syncthreads();
    }

    // epilogue: D row=(lane>>4)*4+j (pixel), col=lane&15 (co). Write co-major, packed 4-pixel chunks.
    long plane = (long)(b * 4 + par) * 512;
#pragma unroll
    for (int mi = 0; mi < 4; ++mi) {
        int gm0 = mt * 128 + wr * 64 + mi * 16 + (lane >> 4) * 4;
#pragma unroll
        for (int ni = 0; ni < 4; ++ni) {
            int co = nt * 128 + wc * 64 + ni * 16 + (lane & 15);
            unsigned short* dst = y1 + (plane + co) * SP + gm0;
            if (gm0 <= 1084) {
                ushort4 pk;
                pk.x = f2bf(acc[mi][ni][0]);
                pk.y = f2bf(acc[mi][ni][1]);
                pk.z = f2bf(acc[mi][ni][2]);
                pk.w = f2bf(acc[mi][ni][3]);
                *(ushort4*)dst = pk;
            } else if (gm0 == 1088) {
                dst[0] = f2bf(acc[mi][ni][0]);
            }
        }
    }
}

// K6: blur(4x4 bilinear, separable) + demod + noise + bias + leaky.
// Per (b, co): stage de-parity-ized 65x65 y into LDS (f32, +1 zero border),
// rolling-register separable filter, coalesced NCHW f32 stores.
__global__ __launch_bounds__(256) void k_blur(const unsigned short* __restrict__ y1,
                                              const float* __restrict__ dcoefs,
                                              const float* __restrict__ bias,
                                              const float* __restrict__ noise,
                                              const float* __restrict__ nstr,
                                              float* __restrict__ out) {
    __shared__ float yl[67 * 69];
    int bid = blockIdx.x;                 // 16 * 64
    int cg = bid & 63, b = bid >> 6;
    int t = threadIdx.x;
    int n = t & 63, mq = t >> 6;
    float ns = nstr[0];

    for (int i = t; i < 67 * 69; i += 256) yl[i] = 0.f;   // zero borders once
    __syncthreads();

    const int Rv[4] = {33, 33, 32, 32};
    const int Sv[4] = {33, 32, 33, 32};
    const float* npb = noise + b * 4096;

    for (int cc = 0; cc < 8; ++cc) {
        int co = cg * 8 + cc;
        // ---- stage 4 parity planes into yl (interior [1..65]x[1..65]) ----
#pragma unroll
        for (int pl = 0; pl < 4; ++pl) {
            int ap = pl >> 1, cq = pl & 1;
            const unsigned short* src = y1 + ((long)((b * 4 + pl) * 512 + co)) * SP;
            int rv = Rv[pl], sv = Sv[pl];
            for (int it = t; it < 273; it += 256) {
                int p0 = it * 4;
                ushort4 v = *(const ushort4*)(src + p0);   // 8B aligned
                unsigned short vv[4] = {v.x, v.y, v.z, v.w};
#pragma unroll
                for (int k = 0; k < 4; ++k) {
                    int p = p0 + k;
                    if (p < 1089) {
                        int r = p / 33;
                        int s = p - r * 33;
                        if (r < rv && s < sv)
                            yl[(2 * r + ap + 1) * 69 + (2 * s + cq + 1)] = bf2f(vv[k]);
                    }
                }
            }
        }
        __syncthreads();

        // ---- separable blur: thread = (column n, row-quarter mq) ----
        float dc = dcoefs[b * 512 + co];
        float bi = bias[co];
        int m0 = mq * 16;
        const float* r0p = &yl[(m0 - 1 + 1) * 69 + n];
        const float* r1p = r0p + 69;
        const float* r2p = r1p + 69;
        float t0 = (r0p[0] + r0p[3]) + 3.f * (r0p[1] + r0p[2]);
        float t1 = (r1p[0] + r1p[3]) + 3.f * (r1p[1] + r1p[2]);
        float t2 = (r2p[0] + r2p[3]) + 3.f * (r2p[1] + r2p[2]);
        float* ob = out + ((long)(b * 512 + co)) * 4096;
#pragma unroll
        for (int k = 0; k < 16; ++k) {
            int m = m0 + k;
            const float* rp = &yl[(m + 3) * 69 + n];      // p = m+2 -> row p+1
            float t3 = (rp[0] + rp[3]) + 3.f * (rp[1] + rp[2]);
            float acc = (t0 + t3) + 3.f * (t1 + t2);
            float val = npb[m * 64 + n] * ns + acc * (0.0625f * dc);
            val = (val + bi) * 1.41421356237309515f;
            ob[m * 64 + n] = (val >= 0.f) ? val : 0.2f * val;
            t0 = t1; t1 = t2; t2 = t3;
        }
        __syncthreads();
    }
}

extern "C" void kernel_launch(void* const* d_in, const int* in_sizes, int n_in,
                              void* d_out, int out_size, void* d_ws, size_t ws_size,
                              hipStream_t stream) {
    (void)in_sizes; (void)n_in; (void)out_size;
    if (ws_size < (size_t)WS_NEED) return;   // workspace too small: fail cleanly
    const float* x      = (const float*)d_in[0];
    const float* w      = (const float*)d_in[1];
    const float* noise  = (const float*)d_in[2];
    const float* aw     = (const float*)d_in[3];
    const float* ab     = (const float*)d_in[4];
    const float* weight = (const float*)d_in[5];
    const float* bias   = (const float*)d_in[6];
    const float* nstr   = (const float*)d_in[7];
    float* out = (float*)d_out;
    char* ws = (char*)d_ws;
    float* styles          = (float*)(ws + O_STYLES);
    float* dcoefs          = (float*)(ws + O_DCOEF);
    unsigned short* xs     = (unsigned short*)(ws + O_XS);
    unsigned short* wp     = (unsigned short*)(ws + O_WP);
    unsigned short* y1     = (unsigned short*)(ws + O_Y1);
    float* wsq             = (float*)(ws + O_WSQ);   // overlapped with y1 head

    hipMemsetAsync(xs, 0, 18939904, stream);
    k_styles<<<32,   256, 0, stream>>>(w, aw, ab, styles);
    k_wprep <<<1024, 256, 0, stream>>>(weight, wsq, wp);
    k_dcoef <<<32,   256, 0, stream>>>(styles, wsq, dcoefs);
    k_xprep <<<2048, 256, 0, stream>>>(x, styles, xs);
    k_conv  <<<2304, 256, 0, stream>>>(xs, wp, y1);
    k_blur  <<<1024, 256, 0, stream>>>(y1, dcoefs, bias, noise, nstr, out);
}

// Round 3
// 212.742 us; speedup vs baseline: 1.8542x; 1.0446x over previous
//
#include <hip/hip_runtime.h>
#include <hip/hip_bf16.h>
#include <stdint.h>

typedef float f32x4 __attribute__((ext_vector_type(4)));
typedef __bf16 bf16x8 __attribute__((ext_vector_type(8)));

#define GLDS16(gp, lp) __builtin_amdgcn_global_load_lds( \
    (const __attribute__((address_space(1))) void*)(gp), \
    (__attribute__((address_space(3))) void*)(lp), 16, 0, 0)

static __device__ __forceinline__ unsigned short f2bf(float f) {
    unsigned int u = __float_as_uint(f);
    u = (u + 0x7fffu + ((u >> 16) & 1u)) >> 16;
    return (unsigned short)u;
}
static __device__ __forceinline__ float bf2f(unsigned short v) {
    return __uint_as_float(((unsigned int)v) << 16);
}

// ---------------- workspace layout (bytes) ----------------
// styles : 16x512 f32                          @ 0
// dcoefs : 16x512 f32                          @ 32768
// xs_pad : 16x34x34x512 bf16 (NHWC, +1 halo)   @ 65536      (18.06 MB)
// wp     : 9x512x512 bf16 ([tap][co][ci])      @ 19005440   (4.5 MB)
// y1T    : 16x4x512x1104 bf16 ([b][pl][co][pix]) @ 23724032 (72.35 MB)
// wsq    : 512x512 f32 — OVERLAPPED into y1T region (consumed before y1 written)
#define O_STYLES 0
#define O_DCOEF  32768
#define O_XS     65536
#define O_WP     19005440
#define O_Y1     23724032
#define O_WSQ    23724032
#define WS_NEED  96075776
#define SP 1104   // y1T pixel stride per co row (2208 B, 8B-aligned)
// conv M axis: gm = b*1092 + pix (pix<1089 real, 1089..1091 junk), M=17472 pad 17664

// K0: styles[b][ci] = w[b]·A[ci]/sqrt(512) + bias[ci]
__global__ __launch_bounds__(256) void k_styles(const float* __restrict__ w,
                                                const float* __restrict__ aw,
                                                const float* __restrict__ ab,
                                                float* __restrict__ styles) {
    int g = blockIdx.x * 256 + threadIdx.x;   // 8192
    int b = g >> 9, ci = g & 511;
    const float4* wr = (const float4*)(w + b * 512);
    const float4* ar = (const float4*)(aw + ci * 512);
    float acc = 0.f;
    for (int k = 0; k < 128; ++k) {
        float4 wv = wr[k], av = ar[k];
        acc += wv.x * av.x + wv.y * av.y + wv.z * av.z + wv.w * av.w;
    }
    styles[g] = acc * 0.04419417382415922f + ab[ci];
}

// K1: per (co,ci): wsq = sum of 9 squared taps; wp[tap][co][ci] = bf16(weight tap)
__global__ __launch_bounds__(256) void k_wprep(const float* __restrict__ weight,
                                               float* __restrict__ wsq,
                                               unsigned short* __restrict__ wp) {
    int g = blockIdx.x * 256 + threadIdx.x;   // 262144 = co*512+ci
    const float* wb = weight + (long)g * 9;
    float v[9]; float s = 0.f;
#pragma unroll
    for (int t = 0; t < 9; ++t) { v[t] = wb[t]; s += v[t] * v[t]; }
    wsq[g] = s;
    // global tap order: par0 (ee): (2,2)(2,0)(0,2)(0,0); par1 (eo): (2,1)(0,1);
    // par2 (oe): (1,2)(1,0); par3 (oo): (1,1)
    const int wri[9] = {2, 2, 0, 0, 2, 0, 1, 1, 1};
    const int wci[9] = {2, 0, 2, 0, 1, 1, 2, 0, 1};
#pragma unroll
    for (int t = 0; t < 9; ++t)
        wp[t * 262144 + g] = f2bf(v[wri[t] * 3 + wci[t]]);
}

// K2: dcoefs[b][co] = rsqrt(sum_ci styles^2 * wsq + 1e-8)
__global__ __launch_bounds__(256) void k_dcoef(const float* __restrict__ styles,
                                               const float* __restrict__ wsq,
                                               float* __restrict__ dcoefs) {
    int g = blockIdx.x * 256 + threadIdx.x;   // 8192
    int b = g >> 9, co = g & 511;
    const float4* sr = (const float4*)(styles + b * 512);
    const float4* qr = (const float4*)(wsq + co * 512);
    float acc = 1e-8f;
    for (int k = 0; k < 128; ++k) {
        float4 sv = sr[k], qv = qr[k];
        acc += sv.x * sv.x * qv.x + sv.y * sv.y * qv.y + sv.z * sv.z * qv.z + sv.w * sv.w * qv.w;
    }
    dcoefs[g] = rsqrtf(acc);
}

// K3: xs_pad[b][i+1][j+1][ci] = bf16(x[b][ci][i][j] * styles[b][ci])  (NCHW->NHWC via LDS)
__global__ __launch_bounds__(256) void k_xprep(const float* __restrict__ x,
                                               const float* __restrict__ styles,
                                               unsigned short* __restrict__ xs) {
    __shared__ float T[128][33];
    int bid = blockIdx.x;                 // 16*32*4
    int cc = bid & 3, i = (bid >> 2) & 31, b = bid >> 7;
    int t = threadIdx.x;
    int ci0 = cc * 128;
    int j_r = t & 31, cl_r = t >> 5;
    const float* xp = x + (((long)(b * 512 + ci0)) * 32 + i) * 32;
#pragma unroll
    for (int it = 0; it < 16; ++it) {
        int cl = cl_r + it * 8;
        T[cl][j_r] = xp[cl * 1024 + j_r];
    }
    __syncthreads();
    int ci_w = t & 127, jg = t >> 7;
    float sv = styles[b * 512 + ci0 + ci_w];
    unsigned short* op = xs + (((long)(b * 34 + (i + 1))) * 34 + 1) * 512 + ci0 + ci_w;
#pragma unroll
    for (int jj = 0; jj < 16; ++jj) {
        int j = jg * 16 + jj;
        op[(long)j * 512] = f2bf(T[ci_w][j] * sv);
    }
}

// K5: stage-1 implicit GEMM, 8-phase pipelined 256x256 tile, BK=64, 8 waves (2Mx4N).
// Per (par): C[gm][co] = sum over taps,ci of xs[...]*wp[...]; gm = b*1092+pix concat axis.
// LDS 128KB dynamic: 2 bufs x {A-k0,A-k1,B-k0,B-k1} 16KB halves. T2 XOR swizzle
// (chunk ^ ((row>>1)&3)) on pre-swizzled global source + swizzled ds_read.
#define G4 asm volatile("s_waitcnt vmcnt(4)" ::: "memory");
#define ST_A(kk) { GLDS16(xsB + sA0 + akt + (kk)*64, smp + nb + (kk)*16384 + t16); \
                   GLDS16(xsB + sA1 + akt + (kk)*64, smp + nb + (kk)*16384 + t16 + 8192); }
#define ST_B(kk) { GLDS16(wpB + sB0 + bkt + (kk)*64, smp + nb + 32768 + (kk)*16384 + t16); \
                   GLDS16(wpB + sB1 + bkt + (kk)*64, smp + nb + 32768 + (kk)*16384 + t16 + 8192); }
#define PHASE(kk, mh, RB, STG, GRD) { \
  _Pragma("unroll") for (int i = 0; i < 4; ++i) \
    av[i] = *(const bf16x8*)(smp + cb + (kk)*16384 + abase + ((mh)*64 + i*16)*64); \
  if (RB) { _Pragma("unroll") for (int j = 0; j < 4; ++j) \
    bv[j] = *(const bf16x8*)(smp + cb + (kk)*16384 + bbase + (j*16)*64); } \
  STG; \
  __builtin_amdgcn_sched_barrier(0); \
  GRD \
  __builtin_amdgcn_s_barrier(); \
  asm volatile("s_waitcnt lgkmcnt(0)" ::: "memory"); \
  __builtin_amdgcn_sched_barrier(0); \
  __builtin_amdgcn_s_setprio(1); \
  _Pragma("unroll") for (int i = 0; i < 4; ++i) \
    _Pragma("unroll") for (int j = 0; j < 4; ++j) \
      acc[(mh)*4 + i][j] = __builtin_amdgcn_mfma_f32_16x16x32_bf16(av[i], bv[j], acc[(mh)*4 + i][j], 0, 0, 0); \
  __builtin_amdgcn_s_setprio(0); \
  __builtin_amdgcn_s_barrier(); }

__global__ __launch_bounds__(512, 2) void k_conv(const unsigned short* __restrict__ xs,
                                                 const unsigned short* __restrict__ wp,
                                                 unsigned short* __restrict__ y1) {
    extern __shared__ __align__(16) char smem[];
    const unsigned char* xsB = (const unsigned char*)xs;
    const unsigned char* wpB = (const unsigned char*)wp;
    char* smp = smem;

    int bid = blockIdx.x;                 // 552 = 4 pars * 69 Mtiles * 2 Ntiles, par-major
    int par, q;
    if (bid < 138)      { par = 0; q = bid; }
    else if (bid < 276) { par = 1; q = bid - 138; }
    else if (bid < 414) { par = 2; q = bid - 276; }
    else                { par = 3; q = bid - 414; }
    int Mtile = q >> 1, Ntile = q & 1;
    int a_par = par >> 1, c_par = par & 1;
    int ntaps = a_par ? (c_par ? 1 : 2) : (c_par ? 2 : 4);
    int tapofs = (par == 0) ? 0 : ((par == 1) ? 4 : ((par == 2) ? 6 : 8));
    int NKT = ntaps << 3;                 // K-tiles of 64 ci

    int tid = threadIdx.x;
    int lane = tid & 63, wave = tid >> 6;
    int wm = wave >> 2, wn = wave & 3;
    int lrow = lane & 15;
    int rchunk = (((lane >> 4) ^ ((lrow >> 1) & 3)) << 4);   // swizzled read chunk
    int abase = (wm * 128 + lrow) * 64 + rchunk;
    int bbase = 32768 + (wn * 64 + lrow) * 64 + rchunk;

    // staging source bases (rows tid>>2 and +128 of the 256-row tile)
    int srow = tid >> 2;
    int schunk = (((tid & 3) ^ ((tid >> 3) & 3)) << 4);      // inverse-swizzled source chunk
    int sA0, sA1;
    {
        unsigned gm = (unsigned)(Mtile * 256 + srow);
        if (gm > 17471u) gm = 17471u;
        unsigned b_ = gm / 1092u; unsigned pix = gm - b_ * 1092u;
        unsigned r = pix / 33u; unsigned s = pix - r * 33u;
        sA0 = (int)(((b_ * 34u + r) * 34u + s) << 10) + schunk;
        gm = (unsigned)(Mtile * 256 + srow + 128);
        if (gm > 17471u) gm = 17471u;
        b_ = gm / 1092u; pix = gm - b_ * 1092u;
        r = pix / 33u; s = pix - r * 33u;
        sA1 = (int)(((b_ * 34u + r) * 34u + s) << 10) + schunk;
    }
    int sB0 = ((Ntile * 256 + srow) << 10) + schunk;
    int sB1 = sB0 + (128 << 10);
    int t16 = tid << 4;

    f32x4 acc[8][4];
#pragma unroll
    for (int i = 0; i < 8; ++i)
#pragma unroll
        for (int j = 0; j < 4; ++j)
            acc[i][j] = (f32x4){0.f, 0.f, 0.f, 0.f};
    bf16x8 av[4], bv[4];

    auto mkA = [&](int kt) -> int {
        int tl = kt >> 3; if (tl >= ntaps) tl = ntaps - 1;
        int cib = kt & 7;
        int dio = a_par ? 1 : (c_par ? tl : (tl >> 1));
        int djo = c_par ? 1 : (a_par ? tl : (tl & 1));
        return dio * 34816 + djo * 1024 + cib * 128;
    };
    auto mkB = [&](int kt) -> long {
        int tl = kt >> 3; if (tl >= ntaps) tl = ntaps - 1;
        return (long)(tapofs + tl) * 524288 + (long)((kt & 7) * 128);
    };

    // prologue: stage K-tile 0 into buf0
    {
        int akt = mkA(0); long bkt = mkB(0); int nb = 0;
        ST_A(0); ST_B(0); ST_A(1); ST_B(1);
    }
    __builtin_amdgcn_sched_barrier(0);
    asm volatile("s_waitcnt vmcnt(4)" ::: "memory");
    __builtin_amdgcn_s_barrier();

    int cur = 0;
    for (int kt = 0; kt < NKT; ++kt) {
        int akt = mkA(kt + 1);
        long bkt = mkB(kt + 1);
        int nb = (cur ^ 1) << 16;
        int cb = cur << 16;
        PHASE(0, 0, 1, ST_A(0), )
        PHASE(0, 1, 0, ST_B(0), G4)
        PHASE(1, 0, 1, ST_A(1), )
        PHASE(1, 1, 0, ST_B(1), G4)
        cur ^= 1;
    }

    // epilogue: acc[mf][nf] row gm = Mtile*256 + wm*128 + mf*16 + (lane>>4)*4 + j
    //           col co = Ntile*256 + wn*64 + nf*16 + (lane&15). Store co-major y1T.
#pragma unroll
    for (int mf = 0; mf < 8; ++mf) {
        int gm0 = Mtile * 256 + wm * 128 + mf * 16 + ((lane >> 4) << 2);
        if (gm0 < 17472) {
            unsigned ug = (unsigned)gm0;
            unsigned bb = ug / 1092u;
            int pix0 = (int)(ug - bb * 1092u);          // multiple of 4
            long rowb = ((long)((bb * 4u + par) * 512) + 0) * SP;
#pragma unroll
            for (int nf = 0; nf < 4; ++nf) {
                int co = Ntile * 256 + wn * 64 + nf * 16 + lrow;
                ushort4 pk;
                pk.x = f2bf(acc[mf][nf][0]);
                pk.y = f2bf(acc[mf][nf][1]);
                pk.z = f2bf(acc[mf][nf][2]);
                pk.w = f2bf(acc[mf][nf][3]);
                *(ushort4*)(y1 + rowb + (long)co * SP + pix0) = pk;
            }
        }
    }
}

// K6: blur(4x4 bilinear, separable) + demod + noise + bias + leaky.
__global__ __launch_bounds__(256) void k_blur(const unsigned short* __restrict__ y1,
                                              const float* __restrict__ dcoefs,
                                              const float* __restrict__ bias,
                                              const float* __restrict__ noise,
                                              const float* __restrict__ nstr,
                                              float* __restrict__ out) {
    __shared__ float yl[67 * 69];
    int bid = blockIdx.x;                 // 16 * 64
    int cg = bid & 63, b = bid >> 6;
    int t = threadIdx.x;
    int n = t & 63, mq = t >> 6;
    float ns = nstr[0];

    for (int i = t; i < 67 * 69; i += 256) yl[i] = 0.f;   // zero borders once
    __syncthreads();

    const int Rv[4] = {33, 33, 32, 32};
    const int Sv[4] = {33, 32, 33, 32};
    const float* npb = noise + b * 4096;

    for (int cc = 0; cc < 8; ++cc) {
        int co = cg * 8 + cc;
        // ---- stage 4 parity planes into yl (interior [1..65]x[1..65]) ----
#pragma unroll
        for (int pl = 0; pl < 4; ++pl) {
            int ap = pl >> 1, cq = pl & 1;
            const unsigned short* src = y1 + ((long)((b * 4 + pl) * 512 + co)) * SP;
            int rv = Rv[pl], sv = Sv[pl];
            for (int it = t; it < 273; it += 256) {
                int p0 = it * 4;
                ushort4 v = *(const ushort4*)(src + p0);   // 8B aligned
                unsigned short vv[4] = {v.x, v.y, v.z, v.w};
#pragma unroll
                for (int k = 0; k < 4; ++k) {
                    int p = p0 + k;
                    if (p < 1089) {
                        int r = p / 33;
                        int s = p - r * 33;
                        if (r < rv && s < sv)
                            yl[(2 * r + ap + 1) * 69 + (2 * s + cq + 1)] = bf2f(vv[k]);
                    }
                }
            }
        }
        __syncthreads();

        // ---- separable blur: thread = (column n, row-quarter mq) ----
        float dc = dcoefs[b * 512 + co];
        float bi = bias[co];
        int m0 = mq * 16;
        const float* r0p = &yl[(m0 - 1 + 1) * 69 + n];
        const float* r1p = r0p + 69;
        const float* r2p = r1p + 69;
        float t0 = (r0p[0] + r0p[3]) + 3.f * (r0p[1] + r0p[2]);
        float t1 = (r1p[0] + r1p[3]) + 3.f * (r1p[1] + r1p[2]);
        float t2 = (r2p[0] + r2p[3]) + 3.f * (r2p[1] + r2p[2]);
        float* ob = out + ((long)(b * 512 + co)) * 4096;
#pragma unroll
        for (int k = 0; k < 16; ++k) {
            int m = m0 + k;
            const float* rp = &yl[(m + 3) * 69 + n];
            float t3 = (rp[0] + rp[3]) + 3.f * (rp[1] + rp[2]);
            float a = (t0 + t3) + 3.f * (t1 + t2);
            float val = npb[m * 64 + n] * ns + a * (0.0625f * dc);
            val = (val + bi) * 1.41421356237309515f;
            ob[m * 64 + n] = (val >= 0.f) ? val : 0.2f * val;
            t0 = t1; t1 = t2; t2 = t3;
        }
        __syncthreads();
    }
}

extern "C" void kernel_launch(void* const* d_in, const int* in_sizes, int n_in,
                              void* d_out, int out_size, void* d_ws, size_t ws_size,
                              hipStream_t stream) {
    (void)in_sizes; (void)n_in; (void)out_size;
    if (ws_size < (size_t)WS_NEED) return;   // workspace too small: fail cleanly
    const float* x      = (const float*)d_in[0];
    const float* w      = (const float*)d_in[1];
    const float* noise  = (const float*)d_in[2];
    const float* aw     = (const float*)d_in[3];
    const float* ab     = (const float*)d_in[4];
    const float* weight = (const float*)d_in[5];
    const float* bias   = (const float*)d_in[6];
    const float* nstr   = (const float*)d_in[7];
    float* out = (float*)d_out;
    char* ws = (char*)d_ws;
    float* styles          = (float*)(ws + O_STYLES);
    float* dcoefs          = (float*)(ws + O_DCOEF);
    unsigned short* xs     = (unsigned short*)(ws + O_XS);
    unsigned short* wp     = (unsigned short*)(ws + O_WP);
    unsigned short* y1     = (unsigned short*)(ws + O_Y1);
    float* wsq             = (float*)(ws + O_WSQ);   // overlapped with y1 head

    hipFuncSetAttribute((const void*)k_conv,
                        hipFuncAttributeMaxDynamicSharedMemorySize, 131072);

    hipMemsetAsync(xs, 0, 18939904, stream);
    k_styles<<<32,   256, 0, stream>>>(w, aw, ab, styles);
    k_wprep <<<1024, 256, 0, stream>>>(weight, wsq, wp);
    k_dcoef <<<32,   256, 0, stream>>>(styles, wsq, dcoefs);
    k_xprep <<<2048, 256, 0, stream>>>(x, styles, xs);
    k_conv  <<<552,  512, 131072, stream>>>(xs, wp, y1);
    k_blur  <<<1024, 256, 0, stream>>>(y1, dcoefs, bias, noise, nstr, out);
}

// Round 4
// 212.641 us; speedup vs baseline: 1.8551x; 1.0005x over previous
//
#include <hip/hip_runtime.h>
#include <hip/hip_bf16.h>
#include <stdint.h>

typedef float f32x4 __attribute__((ext_vector_type(4)));
typedef __bf16 bf16x8 __attribute__((ext_vector_type(8)));

#define GLDS16(gp, lp) __builtin_amdgcn_global_load_lds( \
    (const __attribute__((address_space(1))) void*)(gp), \
    (__attribute__((address_space(3))) void*)(lp), 16, 0, 0)

static __device__ __forceinline__ unsigned short f2bf(float f) {
    unsigned int u = __float_as_uint(f);
    u = (u + 0x7fffu + ((u >> 16) & 1u)) >> 16;
    return (unsigned short)u;
}
static __device__ __forceinline__ float bf2f(unsigned short v) {
    return __uint_as_float(((unsigned int)v) << 16);
}

// ---------------- workspace layout (bytes) ----------------
// styles : 16x512 f32                          @ 0
// dcoefs : 16x512 f32                          @ 32768
// xs_pad : 16x34x34x512 bf16 (NHWC, +1 halo)   @ 65536      (18.06 MB)
// wp     : 9x512x512 bf16 ([tap][co][ci])      @ 19005440   (4.5 MB)
// y1T    : 16x4x512x1104 bf16 ([b][pl][co][pix]) @ 23724032 (72.35 MB)
// wsq    : 512x512 f32 — OVERLAPPED into y1T region (consumed before y1 written)
#define O_STYLES 0
#define O_DCOEF  32768
#define O_XS     65536
#define O_WP     19005440
#define O_Y1     23724032
#define O_WSQ    23724032
#define WS_NEED  96075776
#define SP 1104   // y1T pixel stride per co row (2208 B, 8B-aligned)
// conv M axis: gm = b*1092 + pix (pix<1089 real, 1089..1091 junk), M=17472 pad 17664

// K0: styles[b][ci] = w[b]·A[ci]/sqrt(512) + bias[ci]
__global__ __launch_bounds__(256) void k_styles(const float* __restrict__ w,
                                                const float* __restrict__ aw,
                                                const float* __restrict__ ab,
                                                float* __restrict__ styles) {
    int g = blockIdx.x * 256 + threadIdx.x;   // 8192
    int b = g >> 9, ci = g & 511;
    const float4* wr = (const float4*)(w + b * 512);
    const float4* ar = (const float4*)(aw + ci * 512);
    float acc = 0.f;
    for (int k = 0; k < 128; ++k) {
        float4 wv = wr[k], av = ar[k];
        acc += wv.x * av.x + wv.y * av.y + wv.z * av.z + wv.w * av.w;
    }
    styles[g] = acc * 0.04419417382415922f + ab[ci];
}

// K1: per (co,ci): wsq = sum of 9 squared taps; wp[tap][co][ci] = bf16(weight tap)
__global__ __launch_bounds__(256) void k_wprep(const float* __restrict__ weight,
                                               float* __restrict__ wsq,
                                               unsigned short* __restrict__ wp) {
    int g = blockIdx.x * 256 + threadIdx.x;   // 262144 = co*512+ci
    const float* wb = weight + (long)g * 9;
    float v[9]; float s = 0.f;
#pragma unroll
    for (int t = 0; t < 9; ++t) { v[t] = wb[t]; s += v[t] * v[t]; }
    wsq[g] = s;
    // global tap order: par0 (ee): (2,2)(2,0)(0,2)(0,0); par1 (eo): (2,1)(0,1);
    // par2 (oe): (1,2)(1,0); par3 (oo): (1,1)
    const int wri[9] = {2, 2, 0, 0, 2, 0, 1, 1, 1};
    const int wci[9] = {2, 0, 2, 0, 1, 1, 2, 0, 1};
#pragma unroll
    for (int t = 0; t < 9; ++t)
        wp[t * 262144 + g] = f2bf(v[wri[t] * 3 + wci[t]]);
}

// K2: dcoefs[b][co] = rsqrt(sum_ci styles^2 * wsq + 1e-8)
__global__ __launch_bounds__(256) void k_dcoef(const float* __restrict__ styles,
                                               const float* __restrict__ wsq,
                                               float* __restrict__ dcoefs) {
    int g = blockIdx.x * 256 + threadIdx.x;   // 8192
    int b = g >> 9, co = g & 511;
    const float4* sr = (const float4*)(styles + b * 512);
    const float4* qr = (const float4*)(wsq + co * 512);
    float acc = 1e-8f;
    for (int k = 0; k < 128; ++k) {
        float4 sv = sr[k], qv = qr[k];
        acc += sv.x * sv.x * qv.x + sv.y * sv.y * qv.y + sv.z * sv.z * qv.z + sv.w * sv.w * qv.w;
    }
    dcoefs[g] = rsqrtf(acc);
}

// K3: xs_pad[b][i+1][j+1][ci] = bf16(x[b][ci][i][j] * styles[b][ci])  (NCHW->NHWC via LDS)
__global__ __launch_bounds__(256) void k_xprep(const float* __restrict__ x,
                                               const float* __restrict__ styles,
                                               unsigned short* __restrict__ xs) {
    __shared__ float T[128][33];
    int bid = blockIdx.x;                 // 16*32*4
    int cc = bid & 3, i = (bid >> 2) & 31, b = bid >> 7;
    int t = threadIdx.x;
    int ci0 = cc * 128;
    int j_r = t & 31, cl_r = t >> 5;
    const float* xp = x + (((long)(b * 512 + ci0)) * 32 + i) * 32;
#pragma unroll
    for (int it = 0; it < 16; ++it) {
        int cl = cl_r + it * 8;
        T[cl][j_r] = xp[cl * 1024 + j_r];
    }
    __syncthreads();
    int ci_w = t & 127, jg = t >> 7;
    float sv = styles[b * 512 + ci0 + ci_w];
    unsigned short* op = xs + (((long)(b * 34 + (i + 1))) * 34 + 1) * 512 + ci0 + ci_w;
#pragma unroll
    for (int jj = 0; jj < 16; ++jj) {
        int j = jg * 16 + jj;
        op[(long)j * 512] = f2bf(T[ci_w][j] * sv);
    }
}

// K5: stage-1 implicit GEMM, 256x256 tile, BK=64, 8 waves (2Mx4N).
// 2 phases per K-tile, 32 MFMA per phase (split by K-half, not M-half).
// Counted waits: vmcnt(4) once per phase — drains exactly the half-tile the
// NEXT phase's ds_reads need, keeps 4 loads in flight. Never drains to 0.
// Barriers: P1 {stage->vmcnt->bar->lgkm->MFMA} (no trailing bar: P1 stage hits
// nb, P2 reads cb — no WAR across it); P2 has trailing bar (buffer swap WAR).
#define ST_A(kk) { GLDS16(xsB + sA0 + akt + (kk)*64, smp + nb + (kk)*16384 + t16); \
                   GLDS16(xsB + sA1 + akt + (kk)*64, smp + nb + (kk)*16384 + t16 + 8192); }
#define ST_B(kk) { GLDS16(wpB + sB0 + bkt + (kk)*64, smp + nb + 32768 + (kk)*16384 + t16); \
                   GLDS16(wpB + sB1 + bkt + (kk)*64, smp + nb + 32768 + (kk)*16384 + t16 + 8192); }
#define PHASE2(kk, STG, TAILBAR) { \
  _Pragma("unroll") for (int i = 0; i < 8; ++i) \
    av[i] = *(const bf16x8*)(smp + cb + (kk)*16384 + abase + (i*16)*64); \
  _Pragma("unroll") for (int j = 0; j < 4; ++j) \
    bv[j] = *(const bf16x8*)(smp + cb + (kk)*16384 + bbase + (j*16)*64); \
  STG; \
  __builtin_amdgcn_sched_barrier(0); \
  asm volatile("s_waitcnt vmcnt(4)" ::: "memory"); \
  __builtin_amdgcn_s_barrier(); \
  asm volatile("s_waitcnt lgkmcnt(0)" ::: "memory"); \
  __builtin_amdgcn_sched_barrier(0); \
  __builtin_amdgcn_s_setprio(1); \
  _Pragma("unroll") for (int i = 0; i < 8; ++i) \
    _Pragma("unroll") for (int j = 0; j < 4; ++j) \
      acc[i][j] = __builtin_amdgcn_mfma_f32_16x16x32_bf16(av[i], bv[j], acc[i][j], 0, 0, 0); \
  __builtin_amdgcn_s_setprio(0); \
  if (TAILBAR) __builtin_amdgcn_s_barrier(); }

__global__ __launch_bounds__(512, 2) void k_conv(const unsigned short* __restrict__ xs,
                                                 const unsigned short* __restrict__ wp,
                                                 unsigned short* __restrict__ y1) {
    extern __shared__ __align__(16) char smem[];
    const unsigned char* xsB = (const unsigned char*)xs;
    const unsigned char* wpB = (const unsigned char*)wp;
    char* smp = smem;

    int bid = blockIdx.x;                 // 552 = 4 pars * 69 Mtiles * 2 Ntiles, par-major
    int par, q;
    if (bid < 138)      { par = 0; q = bid; }
    else if (bid < 276) { par = 1; q = bid - 138; }
    else if (bid < 414) { par = 2; q = bid - 276; }
    else                { par = 3; q = bid - 414; }
    int Mtile = q >> 1, Ntile = q & 1;
    int a_par = par >> 1, c_par = par & 1;
    int ntaps = a_par ? (c_par ? 1 : 2) : (c_par ? 2 : 4);
    int tapofs = (par == 0) ? 0 : ((par == 1) ? 4 : ((par == 2) ? 6 : 8));
    int NKT = ntaps << 3;                 // K-tiles of 64 ci

    int tid = threadIdx.x;
    int lane = tid & 63, wave = tid >> 6;
    int wm = wave >> 2, wn = wave & 3;
    int lrow = lane & 15;
    int rchunk = (((lane >> 4) ^ ((lrow >> 1) & 3)) << 4);   // swizzled read chunk
    int abase = (wm * 128 + lrow) * 64 + rchunk;
    int bbase = 32768 + (wn * 64 + lrow) * 64 + rchunk;

    // staging source bases (rows tid>>2 and +128 of the 256-row tile)
    int srow = tid >> 2;
    int schunk = (((tid & 3) ^ ((tid >> 3) & 3)) << 4);      // inverse-swizzled source chunk
    int sA0, sA1;
    {
        unsigned gm = (unsigned)(Mtile * 256 + srow);
        if (gm > 17471u) gm = 17471u;
        unsigned b_ = gm / 1092u; unsigned pix = gm - b_ * 1092u;
        unsigned r = pix / 33u; unsigned s = pix - r * 33u;
        sA0 = (int)(((b_ * 34u + r) * 34u + s) << 10) + schunk;
        gm = (unsigned)(Mtile * 256 + srow + 128);
        if (gm > 17471u) gm = 17471u;
        b_ = gm / 1092u; pix = gm - b_ * 1092u;
        r = pix / 33u; s = pix - r * 33u;
        sA1 = (int)(((b_ * 34u + r) * 34u + s) << 10) + schunk;
    }
    int sB0 = ((Ntile * 256 + srow) << 10) + schunk;
    int sB1 = sB0 + (128 << 10);
    int t16 = tid << 4;

    f32x4 acc[8][4];
#pragma unroll
    for (int i = 0; i < 8; ++i)
#pragma unroll
        for (int j = 0; j < 4; ++j)
            acc[i][j] = (f32x4){0.f, 0.f, 0.f, 0.f};
    bf16x8 av[8], bv[4];

    auto mkA = [&](int kt) -> int {
        int tl = kt >> 3; if (tl >= ntaps) tl = ntaps - 1;
        int cib = kt & 7;
        int dio = a_par ? 1 : (c_par ? tl : (tl >> 1));
        int djo = c_par ? 1 : (a_par ? tl : (tl & 1));
        return dio * 34816 + djo * 1024 + cib * 128;
    };
    auto mkB = [&](int kt) -> long {
        int tl = kt >> 3; if (tl >= ntaps) tl = ntaps - 1;
        return (long)(tapofs + tl) * 524288 + (long)((kt & 7) * 128);
    };

    // prologue: stage K-tile 0 into buf0 (order: A0,B0,A1,B1 — matters for vmcnt)
    {
        int akt = mkA(0); long bkt = mkB(0); int nb = 0;
        ST_A(0); ST_B(0); ST_A(1); ST_B(1);
    }
    __builtin_amdgcn_sched_barrier(0);
    asm volatile("s_waitcnt vmcnt(4)" ::: "memory");   // k0 halves of tile 0 ready
    __builtin_amdgcn_s_barrier();

    int cur = 0;
    for (int kt = 0; kt < NKT; ++kt) {
        int akt = mkA(kt + 1);
        long bkt = mkB(kt + 1);
        int nb = (cur ^ 1) << 16;
        int cb = cur << 16;
        PHASE2(0, { ST_A(0); ST_B(0); }, 0)
        PHASE2(1, { ST_A(1); ST_B(1); }, 1)
        cur ^= 1;
    }

    // epilogue: acc[mf][nf] row gm = Mtile*256 + wm*128 + mf*16 + (lane>>4)*4 + j
    //           col co = Ntile*256 + wn*64 + nf*16 + (lane&15). Store co-major y1T.
#pragma unroll
    for (int mf = 0; mf < 8; ++mf) {
        int gm0 = Mtile * 256 + wm * 128 + mf * 16 + ((lane >> 4) << 2);
        if (gm0 < 17472) {
            unsigned ug = (unsigned)gm0;
            unsigned bb = ug / 1092u;
            int pix0 = (int)(ug - bb * 1092u);          // multiple of 4
            long rowb = ((long)((bb * 4u + par) * 512) + 0) * SP;
#pragma unroll
            for (int nf = 0; nf < 4; ++nf) {
                int co = Ntile * 256 + wn * 64 + nf * 16 + lrow;
                ushort4 pk;
                pk.x = f2bf(acc[mf][nf][0]);
                pk.y = f2bf(acc[mf][nf][1]);
                pk.z = f2bf(acc[mf][nf][2]);
                pk.w = f2bf(acc[mf][nf][3]);
                *(ushort4*)(y1 + rowb + (long)co * SP + pix0) = pk;
            }
        }
    }
}

// K6: blur(4x4 bilinear, separable) + demod + noise + bias + leaky.
__global__ __launch_bounds__(256) void k_blur(const unsigned short* __restrict__ y1,
                                              const float* __restrict__ dcoefs,
                                              const float* __restrict__ bias,
                                              const float* __restrict__ noise,
                                              const float* __restrict__ nstr,
                                              float* __restrict__ out) {
    __shared__ float yl[67 * 69];
    int bid = blockIdx.x;                 // 16 * 64
    int cg = bid & 63, b = bid >> 6;
    int t = threadIdx.x;
    int n = t & 63, mq = t >> 6;
    float ns = nstr[0];

    for (int i = t; i < 67 * 69; i += 256) yl[i] = 0.f;   // zero borders once
    __syncthreads();

    const int Rv[4] = {33, 33, 32, 32};
    const int Sv[4] = {33, 32, 33, 32};
    const float* npb = noise + b * 4096;

    for (int cc = 0; cc < 8; ++cc) {
        int co = cg * 8 + cc;
        // ---- stage 4 parity planes into yl (interior [1..65]x[1..65]) ----
#pragma unroll
        for (int pl = 0; pl < 4; ++pl) {
            int ap = pl >> 1, cq = pl & 1;
            const unsigned short* src = y1 + ((long)((b * 4 + pl) * 512 + co)) * SP;
            int rv = Rv[pl], sv = Sv[pl];
            for (int it = t; it < 273; it += 256) {
                int p0 = it * 4;
                ushort4 v = *(const ushort4*)(src + p0);   // 8B aligned
                unsigned short vv[4] = {v.x, v.y, v.z, v.w};
#pragma unroll
                for (int k = 0; k < 4; ++k) {
                    int p = p0 + k;
                    if (p < 1089) {
                        int r = p / 33;
                        int s = p - r * 33;
                        if (r < rv && s < sv)
                            yl[(2 * r + ap + 1) * 69 + (2 * s + cq + 1)] = bf2f(vv[k]);
                    }
                }
            }
        }
        __syncthreads();

        // ---- separable blur: thread = (column n, row-quarter mq) ----
        float dc = dcoefs[b * 512 + co];
        float bi = bias[co];
        int m0 = mq * 16;
        const float* r0p = &yl[(m0 - 1 + 1) * 69 + n];
        const float* r1p = r0p + 69;
        const float* r2p = r1p + 69;
        float t0 = (r0p[0] + r0p[3]) + 3.f * (r0p[1] + r0p[2]);
        float t1 = (r1p[0] + r1p[3]) + 3.f * (r1p[1] + r1p[2]);
        float t2 = (r2p[0] + r2p[3]) + 3.f * (r2p[1] + r2p[2]);
        float* ob = out + ((long)(b * 512 + co)) * 4096;
#pragma unroll
        for (int k = 0; k < 16; ++k) {
            int m = m0 + k;
            const float* rp = &yl[(m + 3) * 69 + n];
            float t3 = (rp[0] + rp[3]) + 3.f * (rp[1] + rp[2]);
            float a = (t0 + t3) + 3.f * (t1 + t2);
            float val = npb[m * 64 + n] * ns + a * (0.0625f * dc);
            val = (val + bi) * 1.41421356237309515f;
            ob[m * 64 + n] = (val >= 0.f) ? val : 0.2f * val;
            t0 = t1; t1 = t2; t2 = t3;
        }
        __syncthreads();
    }
}

extern "C" void kernel_launch(void* const* d_in, const int* in_sizes, int n_in,
                              void* d_out, int out_size, void* d_ws, size_t ws_size,
                              hipStream_t stream) {
    (void)in_sizes; (void)n_in; (void)out_size;
    if (ws_size < (size_t)WS_NEED) return;   // workspace too small: fail cleanly
    const float* x      = (const float*)d_in[0];
    const float* w      = (const float*)d_in[1];
    const float* noise  = (const float*)d_in[2];
    const float* aw     = (const float*)d_in[3];
    const float* ab     = (const float*)d_in[4];
    const float* weight = (const float*)d_in[5];
    const float* bias   = (const float*)d_in[6];
    const float* nstr   = (const float*)d_in[7];
    float* out = (float*)d_out;
    char* ws = (char*)d_ws;
    float* styles          = (float*)(ws + O_STYLES);
    float* dcoefs          = (float*)(ws + O_DCOEF);
    unsigned short* xs     = (unsigned short*)(ws + O_XS);
    unsigned short* wp     = (unsigned short*)(ws + O_WP);
    unsigned short* y1     = (unsigned short*)(ws + O_Y1);
    float* wsq             = (float*)(ws + O_WSQ);   // overlapped with y1 head

    hipFuncSetAttribute((const void*)k_conv,
                        hipFuncAttributeMaxDynamicSharedMemorySize, 131072);

    hipMemsetAsync(xs, 0, 18939904, stream);
    k_styles<<<32,   256, 0, stream>>>(w, aw, ab, styles);
    k_wprep <<<1024, 256, 0, stream>>>(weight, wsq, wp);
    k_dcoef <<<32,   256, 0, stream>>>(styles, wsq, dcoefs);
    k_xprep <<<2048, 256, 0, stream>>>(x, styles, xs);
    k_conv  <<<552,  512, 131072, stream>>>(xs, wp, y1);
    k_blur  <<<1024, 256, 0, stream>>>(y1, dcoefs, bias, noise, nstr, out);
}